// Round 14
// baseline (924.591 us; speedup 1.0000x reference)
//
#include <hip/hip_runtime.h>

#define MTOK 32768   // 8*4096 tokens
#define CIN  512     // in_ch
#define EMB  256     // emb_ch
#define NCODE 1024
#define VQ   3
#define DELTA 2e-3f  // certified margin; worst-case approx score-diff error ~3e-4

typedef short s16x8 __attribute__((ext_vector_type(8)));
typedef float f32x4 __attribute__((ext_vector_type(4)));
typedef unsigned short u16;
typedef unsigned int u32;

static __device__ __forceinline__ u16 f2bf(float x) {
    unsigned int u = __float_as_uint(x);
    u += 0x7FFF + ((u >> 16) & 1);          // RNE
    return (u16)(u >> 16);
}
static __device__ __forceinline__ float bf2f(u16 h) {
    return __uint_as_float(((unsigned int)h) << 16);
}

// ---------------- init ----------------
__global__ void init_k(double* loss_acc, int* cnt) {
    loss_acc[0] = 0.0;  // sum of min-dists (znorm parts + score parts)
    loss_acc[1] = 0.0;  // sum (z - z_q)^2
    #pragma unroll
    for (int i = 0; i < 8; ++i) cnt[i] = 0;   // [0..2]=pair counts, [3..5]=full counts
}

// ---------------- codebook prep: ||v||^2 (fp64/fp32) + bf16 hi/lo split ----------------
__global__ __launch_bounds__(64) void prep_cb_k(const float* __restrict__ cbs,
                                                double* __restrict__ vnorm64,
                                                float* __restrict__ vnorm32,
                                                u16* __restrict__ cbh,
                                                u16* __restrict__ cbl) {
    int s = blockIdx.x;                       // 0 .. 3*NCODE-1
    const float* row = cbs + (size_t)s * EMB;
    double acc = 0.0;
    for (int k = threadIdx.x; k < EMB; k += 64) {
        float v = row[k];
        double vd = (double)v; acc += vd * vd;
        u16 h = f2bf(v);
        u16 l = f2bf(v - bf2f(h));
        cbh[(size_t)s * EMB + k] = h;
        cbl[(size_t)s * EMB + k] = l;
    }
    #pragma unroll
    for (int off = 32; off > 0; off >>= 1) acc += __shfl_down(acc, off, 64);
    if (threadIdx.x == 0) { vnorm64[s] = acc; vnorm32[s] = (float)acc; }
}

// ---------------- W_in bf16 hi/lo split ----------------
__global__ __launch_bounds__(256) void prep_w_k(const float* __restrict__ W_in,
                                                u16* __restrict__ wh,
                                                u16* __restrict__ wl) {
    int i = blockIdx.x * 256 + threadIdx.x;   // < VQ*EMB*CIN
    float v = W_in[i];
    u16 h = f2bf(v);
    wh[i] = h;
    wl[i] = f2bf(v - bf2f(h));
}

// ---------------- W_in transpose: WinT[s][k][e] = W_in[s][e][k] (exact fp32) ----------------
__global__ __launch_bounds__(256) void prep_wt_k(const float* __restrict__ W_in,
                                                 float* __restrict__ WinT) {
    int i = blockIdx.x * 256 + threadIdx.x;   // < VQ*EMB*CIN
    int s = i / (EMB * CIN);
    int rem = i - s * (EMB * CIN);
    int e = rem / CIN;
    int k = rem - e * CIN;
    WinT[(size_t)s * CIN * EMB + (size_t)k * EMB + e] = W_in[i];
}

// ---------------- T[s] = cb[s] @ W_out[s]^T  (fp64 acc, fp32 store) ----------------
__global__ __launch_bounds__(256) void prep_T_k(const float* __restrict__ cbs,
                                                const float* __restrict__ Wout,
                                                float* __restrict__ T) {
    const int stage = blockIdx.z;
    const float* A = cbs  + (size_t)stage * NCODE * EMB;
    const float* B = Wout + (size_t)stage * CIN * EMB;
    float* C = T + (size_t)stage * NCODE * CIN;
    __shared__ float As[64][33];
    __shared__ float Bs[64][33];
    const int tid = threadIdx.x;
    const int ty = tid >> 4, tx = tid & 15;
    const int m0 = blockIdx.x * 64;
    const int n0 = blockIdx.y * 64;
    const int lrow = tid >> 5, lcol = tid & 31;
    double acc[4][4];
    #pragma unroll
    for (int i = 0; i < 4; ++i)
        #pragma unroll
        for (int j = 0; j < 4; ++j) acc[i][j] = 0.0;

    for (int k0 = 0; k0 < EMB; k0 += 32) {
        __syncthreads();
        #pragma unroll
        for (int t = 0; t < 8; ++t) {
            int r = lrow + 8 * t;
            As[r][lcol] = A[(size_t)(m0 + r) * EMB + k0 + lcol];
            Bs[r][lcol] = B[(size_t)(n0 + r) * EMB + k0 + lcol];
        }
        __syncthreads();
        #pragma unroll
        for (int k = 0; k < 32; ++k) {
            double a[4], b[4];
            #pragma unroll
            for (int i = 0; i < 4; ++i) a[i] = (double)As[ty * 4 + i][k];
            #pragma unroll
            for (int j = 0; j < 4; ++j) b[j] = (double)Bs[tx * 4 + j][k];
            #pragma unroll
            for (int i = 0; i < 4; ++i)
                #pragma unroll
                for (int j = 0; j < 4; ++j) acc[i][j] += a[i] * b[j];
        }
    }
    #pragma unroll
    for (int i = 0; i < 4; ++i) {
        float4 v = make_float4((float)acc[i][0], (float)acc[i][1],
                               (float)acc[i][2], (float)acc[i][3]);
        *reinterpret_cast<float4*>(&C[(size_t)(m0 + ty * 4 + i) * CIN + n0 + tx * 4]) = v;
    }
}

// ================= FUSED v2: zi in LDS (no global round-trip), swizzled =================
// Block = 64 tokens (4 waves x 16). LDS: zi_lds[64][256] u32 (h|l packed, wave-private)
// + one 16-row x 256-k staging tile (W halves in phase 1, cb tiles in phase 2).
// All LDS tiles chunk-XOR swizzled: 16B-chunk' = chunk ^ (row & 7).
__global__ __launch_bounds__(256, 2) void fused_k(const float* __restrict__ z,
                                                  const float* __restrict__ zq,
                                                  const u16* __restrict__ wh,
                                                  const u16* __restrict__ wl,
                                                  const u16* __restrict__ cbh,
                                                  const u16* __restrict__ cbl,
                                                  const float* __restrict__ vnorm32,
                                                  int* __restrict__ idx,
                                                  int* __restrict__ idx_sum,
                                                  float* __restrict__ mind,
                                                  int* __restrict__ flagged,
                                                  int* __restrict__ cnt,
                                                  int* __restrict__ fullList,
                                                  int* __restrict__ cntF,
                                                  int* __restrict__ cand2,
                                                  double* __restrict__ loss_acc,
                                                  int stage0, int cumprod) {
    __shared__ __align__(16) u32 zi_lds[64][256];   // 65536 B
    __shared__ __align__(16) u16 sbh[16][256];      // 8192 B
    __shared__ __align__(16) u16 sbl[16][256];      // 8192 B  (total 80 KB exact)
    const int tid = threadIdx.x;
    const int w = tid >> 6;
    const int l = tid & 63;
    const int col = l & 15;
    const int g = l >> 4;
    const int mw = blockIdx.x * 64 + w * 16;
    const int sr = tid >> 4, sq = tid & 15;
    const int swz_w = (sq ^ (sr & 7)) << 3;         // staging write: element offset in row sr

    // ---------- Phase 1: zi = (z - zq) @ W^T -> zi_lds (packed bf16 h|l) ----------
    {
        s16x8 ah[16], al[16];
        const float* zr = z  + (size_t)(mw + col) * CIN + g * 8;
        const float* qr = zq + (size_t)(mw + col) * CIN + g * 8;
        #pragma unroll
        for (int kc = 0; kc < 16; ++kc) {
            float4 f0 = *reinterpret_cast<const float4*>(zr + kc * 32);
            float4 f1 = *reinterpret_cast<const float4*>(zr + kc * 32 + 4);
            float f[8] = {f0.x, f0.y, f0.z, f0.w, f1.x, f1.y, f1.z, f1.w};
            if (!stage0) {
                float4 q0 = *reinterpret_cast<const float4*>(qr + kc * 32);
                float4 q1 = *reinterpret_cast<const float4*>(qr + kc * 32 + 4);
                f[0] -= q0.x; f[1] -= q0.y; f[2] -= q0.z; f[3] -= q0.w;
                f[4] -= q1.x; f[5] -= q1.y; f[6] -= q1.z; f[7] -= q1.w;
            }
            #pragma unroll
            for (int j = 0; j < 8; ++j) {
                u16 h = f2bf(f[j]);
                u16 lo = f2bf(f[j] - bf2f(h));
                ah[kc][j] = (short)h; al[kc][j] = (short)lo;
            }
        }

        // W staging: stage S = nt*2 + kh -> rows nt*16+sr, k-half kh (256 k)
        uint4 h0, h1, l0, l1;
#define WLOAD(S) do { int nt_ = (S) >> 1, kh_ = (S) & 1;                               \
    const u16* th = wh + (size_t)(nt_ * 16 + sr) * CIN + kh_ * 256 + sq * 8;           \
    const u16* tl = wl + (size_t)(nt_ * 16 + sr) * CIN + kh_ * 256 + sq * 8;           \
    h0 = *(const uint4*)(th);  h1 = *(const uint4*)(th + 128);                         \
    l0 = *(const uint4*)(tl);  l1 = *(const uint4*)(tl + 128); } while (0)
#define SWRITE() do {                                                                  \
    *(uint4*)&sbh[sr][swz_w] = h0;  *(uint4*)&sbh[sr][swz_w + 128] = h1;               \
    *(uint4*)&sbl[sr][swz_w] = l0;  *(uint4*)&sbl[sr][swz_w + 128] = l1; } while (0)
        WLOAD(0);

        double zn = 0.0;
        for (int nt = 0; nt < 16; ++nt) {
            f32x4 a0 = {0.f, 0.f, 0.f, 0.f};
            f32x4 a1 = {0.f, 0.f, 0.f, 0.f};
            f32x4 a2 = {0.f, 0.f, 0.f, 0.f};
            #pragma unroll
            for (int kh = 0; kh < 2; ++kh) {
                const int S = nt * 2 + kh;
                __syncthreads();                 // prev tile reads done
                SWRITE();
                __syncthreads();                 // tile ready
                if (S + 1 < 32) WLOAD(S + 1);    // issue-early (T14)
                #pragma unroll
                for (int kc = 0; kc < 8; ++kc) {
                    const int off = (((g + 4 * kc) ^ (col & 7)) << 3);
                    s16x8 Bh = *(const s16x8*)&sbh[col][off];
                    s16x8 Bl = *(const s16x8*)&sbl[col][off];
                    const int ka = kh * 8 + kc;
                    a0 = __builtin_amdgcn_mfma_f32_16x16x32_bf16(ah[ka], Bh, a0, 0, 0, 0);
                    a1 = __builtin_amdgcn_mfma_f32_16x16x32_bf16(al[ka], Bh, a1, 0, 0, 0);
                    a2 = __builtin_amdgcn_mfma_f32_16x16x32_bf16(ah[ka], Bl, a2, 0, 0, 0);
                }
            }
            #pragma unroll
            for (int r = 0; r < 4; ++r) {
                float v = a0[r] + a1[r] + a2[r];
                u16 h = f2bf(v);
                u16 lo = f2bf(v - bf2f(h));
                const int trow = w * 16 + g * 4 + r;
                const int coff = (((nt * 4 + (col >> 2)) ^ (trow & 7)) << 2) + (col & 3);
                zi_lds[trow][coff] = (u32)h | ((u32)lo << 16);
                zn += (double)v * (double)v;
            }
        }
#undef WLOAD
#undef SWRITE
        #pragma unroll
        for (int off = 32; off > 0; off >>= 1) zn += __shfl_down(zn, off, 64);
        if (l == 0) atomicAdd(loss_acc, zn);
    }

    // ---------- Phase 2: prefilter; A-frags from wave-private zi_lds ----------
    s16x8 ah[8], al[8];
    {
        const int t = w * 16 + col;
        #pragma unroll
        for (int kc = 0; kc < 8; ++kc) {
            const int ck0 = g * 2 + kc * 8;
            uint4 u0 = *(const uint4*)&zi_lds[t][((ck0 ^ (t & 7)) << 2)];
            uint4 u1 = *(const uint4*)&zi_lds[t][(((ck0 + 1) ^ (t & 7)) << 2)];
            u32 u[8] = {u0.x, u0.y, u0.z, u0.w, u1.x, u1.y, u1.z, u1.w};
            #pragma unroll
            for (int j = 0; j < 8; ++j) {
                ah[kc][j] = (short)(u[j] & 0xffffu);
                al[kc][j] = (short)(u[j] >> 16);
            }
        }
    }

    float b1[4] = {1e30f, 1e30f, 1e30f, 1e30f};
    float b2[4] = {1e30f, 1e30f, 1e30f, 1e30f};
    float b3[4] = {1e30f, 1e30f, 1e30f, 1e30f};
    int   i1[4] = {0, 0, 0, 0};
    int   i2[4] = {0, 0, 0, 0};

    uint4 h0, h1, l0, l1;
#define PLOAD(CT) do {                                                                 \
    const u16* th = cbh + (size_t)((CT) * 16 + sr) * EMB + sq * 8;                     \
    const u16* tl = cbl + (size_t)((CT) * 16 + sr) * EMB + sq * 8;                     \
    h0 = *(const uint4*)(th);  h1 = *(const uint4*)(th + 128);                         \
    l0 = *(const uint4*)(tl);  l1 = *(const uint4*)(tl + 128); } while (0)
#define SWRITE() do {                                                                  \
    *(uint4*)&sbh[sr][swz_w] = h0;  *(uint4*)&sbh[sr][swz_w + 128] = h1;               \
    *(uint4*)&sbl[sr][swz_w] = l0;  *(uint4*)&sbl[sr][swz_w + 128] = l1; } while (0)
    PLOAD(0);

    for (int ct = 0; ct < 64; ++ct) {
        __syncthreads();                         // prev tile reads done (and phase-1 tail)
        SWRITE();
        __syncthreads();                         // tile ct ready
        if (ct + 1 < 64) PLOAD(ct + 1);
        const float vn = vnorm32[ct * 16 + col];
        f32x4 a0 = {0.f, 0.f, 0.f, 0.f};
        f32x4 a1 = {0.f, 0.f, 0.f, 0.f};
        f32x4 a2 = {0.f, 0.f, 0.f, 0.f};
        #pragma unroll
        for (int kc = 0; kc < 8; ++kc) {
            const int off = (((g + 4 * kc) ^ (col & 7)) << 3);
            s16x8 Bh = *(const s16x8*)&sbh[col][off];
            s16x8 Bl = *(const s16x8*)&sbl[col][off];
            a0 = __builtin_amdgcn_mfma_f32_16x16x32_bf16(ah[kc], Bh, a0, 0, 0, 0);
            a1 = __builtin_amdgcn_mfma_f32_16x16x32_bf16(al[kc], Bh, a1, 0, 0, 0);
            a2 = __builtin_amdgcn_mfma_f32_16x16x32_bf16(ah[kc], Bl, a2, 0, 0, 0);
        }
        #pragma unroll
        for (int r = 0; r < 4; ++r) {
            float sc = vn - 2.f * (a0[r] + a1[r] + a2[r]);
            int c = ct * 16 + col;
            if (sc < b1[r]) { b3[r] = b2[r]; b2[r] = b1[r]; i2[r] = i1[r]; b1[r] = sc; i1[r] = c; }
            else if (sc < b2[r]) { b3[r] = b2[r]; b2[r] = sc; i2[r] = c; }
            else b3[r] = fminf(b3[r], sc);
        }
    }
#undef PLOAD
#undef SWRITE

    // cross-lane top-3 merge over the 16 lanes of each token group
    #pragma unroll
    for (int off = 1; off < 16; off <<= 1) {
        #pragma unroll
        for (int r = 0; r < 4; ++r) {
            float c1 = __shfl_xor(b1[r], off, 64);
            int   j1 = __shfl_xor(i1[r], off, 64);
            float c2 = __shfl_xor(b2[r], off, 64);
            int   j2 = __shfl_xor(i2[r], off, 64);
            float c3 = __shfl_xor(b3[r], off, 64);
            float nb1, nb2, nb3; int ni1, ni2;
            if (c1 < b1[r] || (c1 == b1[r] && j1 < i1[r])) {
                nb1 = c1; ni1 = j1;
                if (b1[r] < c2 || (b1[r] == c2 && i1[r] < j2)) {
                    nb2 = b1[r]; ni2 = i1[r]; nb3 = fminf(b2[r], c2);
                } else {
                    nb2 = c2; ni2 = j2; nb3 = fminf(b1[r], c3);
                }
            } else {
                nb1 = b1[r]; ni1 = i1[r];
                if (c1 < b2[r] || (c1 == b2[r] && j1 < i2[r])) {
                    nb2 = c1; ni2 = j1; nb3 = fminf(b2[r], c2);
                } else {
                    nb2 = b2[r]; ni2 = i2[r]; nb3 = fminf(c1, b3[r]);
                }
            }
            b1[r] = nb1; b2[r] = nb2; b3[r] = nb3; i1[r] = ni1; i2[r] = ni2;
        }
    }

    double lsum = 0.0;
    if (col == 0) {
        #pragma unroll
        for (int r = 0; r < 4; ++r) {
            int m = mw + g * 4 + r;
            idx[m] = i1[r];
            if (stage0) idx_sum[m] = i1[r];
            else        idx_sum[m] += i1[r] * cumprod;
            mind[m] = b1[r];                 // score-only part
            lsum += (double)b1[r];
            if (b2[r] - b1[r] < DELTA) {
                if (b3[r] - b1[r] < DELTA) {
                    int slot = atomicAdd(cntF, 1);
                    fullList[slot] = m;
                } else {
                    int slot = atomicAdd(cnt, 1);
                    flagged[slot] = m;
                    cand2[m] = i2[r];
                }
            }
        }
    }
    #pragma unroll
    for (int off = 32; off > 0; off >>= 1) lsum += __shfl_down(lsum, off, 64);
    if (l == 0) atomicAdd(loss_acc, lsum);
}

// ---------------- exact fp64 pair rescan, batched 8 tokens/block ----------------
__global__ __launch_bounds__(256) void rescan_pair_k(const float* __restrict__ z,
                                                     const float* __restrict__ zqv,
                                                     const float* __restrict__ WinT,
                                                     const float* __restrict__ cb,
                                                     const double* __restrict__ vnorm64,
                                                     const int* __restrict__ flagged,
                                                     const int* __restrict__ cnt,
                                                     const int* __restrict__ cand2,
                                                     int* __restrict__ idx,
                                                     int* __restrict__ idx_sum,
                                                     float* __restrict__ mind,
                                                     double* __restrict__ loss_acc,
                                                     int cumprod, int stage0) {
    __shared__ double r64[8][CIN];           // 32 KB; first 16 KB reused as zi64[8][256]
    __shared__ int mArr[8], cAArr[8], cBArr[8];
    double* zi_l = &r64[0][0];               // alias (used after sync)
    const int tid = threadIdx.x;
    const int w = tid >> 6, l = tid & 63;
    const int n = *cnt;

    for (int jb = blockIdx.x; jb * 8 < n; jb += gridDim.x) {
        const int nt = min(8, n - jb * 8);
        __syncthreads();                     // protect LDS reuse across jb
        if (tid < nt) {
            int m = flagged[jb * 8 + tid];
            mArr[tid] = m;
            cAArr[tid] = idx[m]; cBArr[tid] = cand2[m];
        }
        __syncthreads();
        // stage residuals (coalesced): thread covers k = tid, tid+256
        for (int t = 0; t < nt; ++t) {
            const int m = mArr[t];
            #pragma unroll
            for (int h = 0; h < 2; ++h) {
                int k = tid + h * 256;
                float rv = z[(size_t)m * CIN + k];
                if (!stage0) rv -= zqv[(size_t)m * CIN + k];   // fp32 subtract (matches ref)
                r64[t][k] = (double)rv;
            }
        }
        __syncthreads();
        // zi64: thread e = tid computes 8 dots; WinT rows read coalesced, r64 broadcast
        double acc[8] = {0, 0, 0, 0, 0, 0, 0, 0};
        #pragma unroll 4
        for (int k = 0; k < CIN; ++k) {
            double wv = (double)WinT[(size_t)k * EMB + tid];
            #pragma unroll
            for (int t = 0; t < 8; ++t) acc[t] += r64[t][k] * wv;
        }
        __syncthreads();
        #pragma unroll
        for (int t = 0; t < 8; ++t) zi_l[t * 256 + tid] = acc[t];
        __syncthreads();

        // wave w handles tokens t = w, w+4
        for (int t = w; t < nt; t += 4) {
            const int cA = cAArr[t], cB = cBArr[t], m = mArr[t];
            const double* zt = zi_l + t * 256;
            float4 vA = *(const float4*)(cb + (size_t)cA * EMB + 4 * l);
            float4 vB = *(const float4*)(cb + (size_t)cB * EMB + 4 * l);
            double z0 = zt[4 * l], z1 = zt[4 * l + 1];
            double z2 = zt[4 * l + 2], z3 = zt[4 * l + 3];
            double sA = z0 * (double)vA.x + z1 * (double)vA.y
                      + z2 * (double)vA.z + z3 * (double)vA.w;
            double sB = z0 * (double)vB.x + z1 * (double)vB.y
                      + z2 * (double)vB.z + z3 * (double)vB.w;
            #pragma unroll
            for (int off = 1; off < 64; off <<= 1) {
                sA += __shfl_xor(sA, off, 64);
                sB += __shfl_xor(sB, off, 64);
            }
            if (l == 0) {
                double dA = vnorm64[cA] - 2.0 * sA;
                double dB = vnorm64[cB] - 2.0 * sB;
                int bi; double best;
                if (dB < dA || (dB == dA && cB < cA)) { bi = cB; best = dB; }
                else                                   { bi = cA; best = dA; }
                int oldI = idx[m];
                if (bi != oldI) { idx[m] = bi; idx_sum[m] += (bi - oldI) * cumprod; }
                atomicAdd(loss_acc, best - (double)mind[m]);
                mind[m] = (float)best;
            }
        }
    }
}

// ---------------- exact fp64 full scan, one block per full token, thread-per-code ----------------
__global__ __launch_bounds__(256) void fullscan_k(const float* __restrict__ z,
                                                  const float* __restrict__ zqv,
                                                  const float* __restrict__ WinT,
                                                  const float* __restrict__ cb,
                                                  const double* __restrict__ vnorm64,
                                                  const int* __restrict__ fullList,
                                                  const int* __restrict__ cntF,
                                                  int* __restrict__ idx,
                                                  int* __restrict__ idx_sum,
                                                  float* __restrict__ mind,
                                                  double* __restrict__ loss_acc,
                                                  int cumprod, int stage0) {
    __shared__ double r64[CIN];
    __shared__ double zi64[EMB];
    __shared__ double sred[256];
    __shared__ int ired[256];
    const int tid = threadIdx.x;
    const int n = *cntF;

    for (int j = blockIdx.x; j < n; j += gridDim.x) {
        const int m = fullList[j];
        __syncthreads();                     // protect LDS reuse across j
        #pragma unroll
        for (int h = 0; h < 2; ++h) {
            int k = tid + h * 256;
            float rv = z[(size_t)m * CIN + k];
            if (!stage0) rv -= zqv[(size_t)m * CIN + k];
            r64[k] = (double)rv;
        }
        __syncthreads();
        {
            double acc = 0.0;
            #pragma unroll 8
            for (int k = 0; k < CIN; ++k)
                acc += r64[k] * (double)WinT[(size_t)k * EMB + tid];
            zi64[tid] = acc;
        }
        __syncthreads();
        // thread t scores codes {t, 256+t, 512+t, 768+t} (ascending per thread)
        double best = 1e300; int bi = 0;
        #pragma unroll
        for (int q = 0; q < 4; ++q) {
            const int c = q * 256 + tid;
            const float* row = cb + (size_t)c * EMB;
            double s0 = 0, s1 = 0, s2 = 0, s3 = 0;
            #pragma unroll 4
            for (int e = 0; e < EMB; e += 4) {
                float4 v = *(const float4*)(row + e);
                s0 += zi64[e]     * (double)v.x;
                s1 += zi64[e + 1] * (double)v.y;
                s2 += zi64[e + 2] * (double)v.z;
                s3 += zi64[e + 3] * (double)v.w;
            }
            double sc = vnorm64[c] - 2.0 * ((s0 + s1) + (s2 + s3));
            if (sc < best) { best = sc; bi = c; }
        }
        sred[tid] = best; ired[tid] = bi;
        __syncthreads();
        for (int off = 128; off > 0; off >>= 1) {
            if (tid < off) {
                double ob = sred[tid + off]; int oi = ired[tid + off];
                if (ob < sred[tid] || (ob == sred[tid] && oi < ired[tid])) {
                    sred[tid] = ob; ired[tid] = oi;
                }
            }
            __syncthreads();
        }
        if (tid == 0) {
            int oldI = idx[m], bi2 = ired[0];
            double best2 = sred[0];
            if (bi2 != oldI) { idx[m] = bi2; idx_sum[m] += (bi2 - oldI) * cumprod; }
            atomicAdd(loss_acc, best2 - (double)mind[m]);
            mind[m] = (float)best2;
        }
    }
}

// ---------------- zq (+)= T[idx]  (row gather); last stage also sums (z - zq)^2 ----------------
__global__ __launch_bounds__(256) void gather_k(const float* __restrict__ T,
                                                const int* __restrict__ idx,
                                                const float* __restrict__ z,
                                                float* __restrict__ zq,
                                                int stage0, int last,
                                                double* __restrict__ loss_acc) {
    __shared__ double red[256];
    int m = blockIdx.x * 16 + (threadIdx.x >> 4);
    int q = threadIdx.x & 15;
    const float* src = T + (size_t)idx[m] * CIN;
    float* dst = zq + (size_t)m * CIN;
    double s = 0.0;
    #pragma unroll
    for (int it = 0; it < 8; ++it) {
        int off = it * 64 + q * 4;
        float4 t = *reinterpret_cast<const float4*>(src + off);
        if (!stage0) {
            float4 o = *reinterpret_cast<const float4*>(dst + off);
            t.x += o.x; t.y += o.y; t.z += o.z; t.w += o.w;
        }
        *reinterpret_cast<float4*>(dst + off) = t;
        if (last) {
            float4 zv = *reinterpret_cast<const float4*>(z + (size_t)m * CIN + off);
            double d0 = (double)zv.x - (double)t.x;
            double d1 = (double)zv.y - (double)t.y;
            double d2 = (double)zv.z - (double)t.z;
            double d3 = (double)zv.w - (double)t.w;
            s += d0 * d0 + d1 * d1 + d2 * d2 + d3 * d3;
        }
    }
    if (last) {
        red[threadIdx.x] = s;
        __syncthreads();
        for (int off = 128; off > 0; off >>= 1) {
            if (threadIdx.x < off) red[threadIdx.x] += red[threadIdx.x + off];
            __syncthreads();
        }
        if (threadIdx.x == 0) atomicAdd(loss_acc + 1, red[0]);
    }
}

// ---------------- finalize ----------------
__global__ void final_k(const int* __restrict__ idx_sum,
                        const double* __restrict__ loss_acc,
                        float* __restrict__ out) {
    int i = blockIdx.x * blockDim.x + threadIdx.x;
    if (i < MTOK) out[MTOK * CIN + i] = (float)idx_sum[i];
    if (i == 0) {
        double loss = 2.0 * loss_acc[0] / (3.0 * (double)MTOK * (double)EMB)
                    + loss_acc[1] / ((double)MTOK * (double)CIN);
        out[MTOK * CIN + MTOK] = (float)loss;
    }
}

extern "C" void kernel_launch(void* const* d_in, const int* in_sizes, int n_in,
                              void* d_out, int out_size, void* d_ws, size_t ws_size,
                              hipStream_t stream) {
    const float* z     = (const float*)d_in[0];
    const float* W_in  = (const float*)d_in[1];
    const float* W_out = (const float*)d_in[2];
    const float* cbs   = (const float*)d_in[3];
    float* out = (float*)d_out;
    char* ws = (char*)d_ws;

    // ws layout (16B-aligned)
    double* vnorm64  = (double*)ws;                               // 24576
    double* loss_acc = (double*)(ws + 24576);                     // 16
    int*    cnt      = (int*)(ws + 24592);                        // 32 ([0..2] pair, [3..5] full)
    float*  vnorm32  = (float*)(ws + 24624);                      // 12288 -> 36912
    u16*    cbh      = (u16*)(ws + 36912);                        // 1572864 -> 1609776
    u16*    cbl      = (u16*)(ws + 1609776);                      // 1572864 -> 3182640
    u16*    wh       = (u16*)(ws + 3182640);                      // 786432 -> 3969072
    u16*    wl       = (u16*)(ws + 3969072);                      // 786432 -> 4755504
    float*  WinT     = (float*)(ws + 4755504);                    // 1572864 -> 6328368
    float*  T        = (float*)(ws + 6328368);                    // 6291456 -> 12619824
    char*   p        = ws + 12619824;
    int*    idx      = (int*)p;                                   // 131072
    int*    idx_sum  = (int*)(p + 131072);                        // 131072
    int*    flagged  = (int*)(p + 262144);                        // 131072
    float*  mind     = (float*)(p + 393216);                      // 131072
    int*    cand2    = (int*)(p + 524288);                        // 131072
    int*    fullList = (int*)(p + 655360);                        // 131072

    float* zq = out;  // z_q lives in d_out[0 .. MTOK*CIN)

    init_k<<<dim3(1), dim3(1), 0, stream>>>(loss_acc, cnt);
    prep_cb_k<<<dim3(VQ * NCODE), dim3(64), 0, stream>>>(cbs, vnorm64, vnorm32, cbh, cbl);
    prep_w_k<<<dim3(VQ * EMB * CIN / 256), dim3(256), 0, stream>>>(W_in, wh, wl);
    prep_wt_k<<<dim3(VQ * EMB * CIN / 256), dim3(256), 0, stream>>>(W_in, WinT);
    prep_T_k<<<dim3(NCODE / 64, CIN / 64, VQ), dim3(256), 0, stream>>>(cbs, W_out, T);

    const int cumprod[VQ] = {1, 1024, 1024 * 1024};
    for (int i = 0; i < VQ; ++i) {
        const float* cb = cbs + (size_t)i * NCODE * EMB;
        fused_k<<<dim3(MTOK / 64), dim3(256), 0, stream>>>(
            z, zq, wh + (size_t)i * EMB * CIN, wl + (size_t)i * EMB * CIN,
            cbh + (size_t)i * NCODE * EMB, cbl + (size_t)i * NCODE * EMB,
            vnorm32 + i * NCODE, idx, idx_sum, mind, flagged, cnt + i,
            fullList, cnt + 3 + i, cand2, loss_acc, i == 0 ? 1 : 0, cumprod[i]);
        rescan_pair_k<<<dim3(512), dim3(256), 0, stream>>>(
            z, zq, WinT + (size_t)i * EMB * CIN, cb, vnorm64 + i * NCODE,
            flagged, cnt + i, cand2, idx, idx_sum, mind, loss_acc, cumprod[i],
            i == 0 ? 1 : 0);
        fullscan_k<<<dim3(256), dim3(256), 0, stream>>>(
            z, zq, WinT + (size_t)i * EMB * CIN, cb, vnorm64 + i * NCODE,
            fullList, cnt + 3 + i, idx, idx_sum, mind, loss_acc, cumprod[i],
            i == 0 ? 1 : 0);
        gather_k<<<dim3(MTOK / 16), dim3(256), 0, stream>>>(
            T + (size_t)i * NCODE * CIN, idx, z, zq, i == 0 ? 1 : 0,
            i == VQ - 1 ? 1 : 0, loss_acc);
    }
    final_k<<<dim3(MTOK / 256), dim3(256), 0, stream>>>(idx_sum, loss_acc, out);
}

// Round 15
// 844.014 us; speedup vs baseline: 1.0955x; 1.0955x over previous
//
#include <hip/hip_runtime.h>

#define MTOK 32768   // 8*4096 tokens
#define CIN  512     // in_ch
#define EMB  256     // emb_ch
#define NCODE 1024
#define VQ   3
#define DELTA 2e-3f  // certified margin; worst-case approx score-diff error ~3e-4

typedef short s16x8 __attribute__((ext_vector_type(8)));
typedef float f32x4 __attribute__((ext_vector_type(4)));
typedef unsigned short u16;
typedef unsigned int u32;

static __device__ __forceinline__ u16 f2bf(float x) {
    unsigned int u = __float_as_uint(x);
    u += 0x7FFF + ((u >> 16) & 1);          // RNE
    return (u16)(u >> 16);
}
static __device__ __forceinline__ float bf2f(u16 h) {
    return __uint_as_float(((unsigned int)h) << 16);
}
// cheap truncation split: v ~= bf2f(h) + bf2f(lo), residual <= 2^-16 |v|
static __device__ __forceinline__ void split2(float v, u16& h, u16& lo) {
    u32 u = __float_as_uint(v);
    h = (u16)(u >> 16);
    float d = v - __uint_as_float(u & 0xFFFF0000u);   // exact (Sterbenz)
    lo = (u16)(__float_as_uint(d) >> 16);
}

// ---------------- init ----------------
__global__ void init_k(double* loss_acc, int* cnt) {
    loss_acc[0] = 0.0;  // sum of min-dists (znorm parts + score parts)
    loss_acc[1] = 0.0;  // sum (z - z_q)^2
    #pragma unroll
    for (int i = 0; i < 8; ++i) cnt[i] = 0;   // [0..2]=pair counts, [3..5]=full counts
}

// ---------------- codebook prep: ||v||^2 (fp64/fp32) + bf16 hi/lo split ----------------
__global__ __launch_bounds__(64) void prep_cb_k(const float* __restrict__ cbs,
                                                double* __restrict__ vnorm64,
                                                float* __restrict__ vnorm32,
                                                u16* __restrict__ cbh,
                                                u16* __restrict__ cbl) {
    int s = blockIdx.x;                       // 0 .. 3*NCODE-1
    const float* row = cbs + (size_t)s * EMB;
    double acc = 0.0;
    for (int k = threadIdx.x; k < EMB; k += 64) {
        float v = row[k];
        double vd = (double)v; acc += vd * vd;
        u16 h = f2bf(v);
        u16 l = f2bf(v - bf2f(h));
        cbh[(size_t)s * EMB + k] = h;
        cbl[(size_t)s * EMB + k] = l;
    }
    #pragma unroll
    for (int off = 32; off > 0; off >>= 1) acc += __shfl_down(acc, off, 64);
    if (threadIdx.x == 0) { vnorm64[s] = acc; vnorm32[s] = (float)acc; }
}

// ---------------- W_in bf16 hi/lo split ----------------
__global__ __launch_bounds__(256) void prep_w_k(const float* __restrict__ W_in,
                                                u16* __restrict__ wh,
                                                u16* __restrict__ wl) {
    int i = blockIdx.x * 256 + threadIdx.x;   // < VQ*EMB*CIN
    float v = W_in[i];
    u16 h = f2bf(v);
    wh[i] = h;
    wl[i] = f2bf(v - bf2f(h));
}

// ---------------- W_in transpose: WinT[s][k][e] = W_in[s][e][k] (exact fp32) ----------------
__global__ __launch_bounds__(256) void prep_wt_k(const float* __restrict__ W_in,
                                                 float* __restrict__ WinT) {
    int i = blockIdx.x * 256 + threadIdx.x;   // < VQ*EMB*CIN
    int s = i / (EMB * CIN);
    int rem = i - s * (EMB * CIN);
    int e = rem / CIN;
    int k = rem - e * CIN;
    WinT[(size_t)s * CIN * EMB + (size_t)k * EMB + e] = W_in[i];
}

// ---------------- T[s] = cb[s] @ W_out[s]^T  (fp64 acc, fp32 store) ----------------
__global__ __launch_bounds__(256) void prep_T_k(const float* __restrict__ cbs,
                                                const float* __restrict__ Wout,
                                                float* __restrict__ T) {
    const int stage = blockIdx.z;
    const float* A = cbs  + (size_t)stage * NCODE * EMB;
    const float* B = Wout + (size_t)stage * CIN * EMB;
    float* C = T + (size_t)stage * NCODE * CIN;
    __shared__ float As[64][33];
    __shared__ float Bs[64][33];
    const int tid = threadIdx.x;
    const int ty = tid >> 4, tx = tid & 15;
    const int m0 = blockIdx.x * 64;
    const int n0 = blockIdx.y * 64;
    const int lrow = tid >> 5, lcol = tid & 31;
    double acc[4][4];
    #pragma unroll
    for (int i = 0; i < 4; ++i)
        #pragma unroll
        for (int j = 0; j < 4; ++j) acc[i][j] = 0.0;

    for (int k0 = 0; k0 < EMB; k0 += 32) {
        __syncthreads();
        #pragma unroll
        for (int t = 0; t < 8; ++t) {
            int r = lrow + 8 * t;
            As[r][lcol] = A[(size_t)(m0 + r) * EMB + k0 + lcol];
            Bs[r][lcol] = B[(size_t)(n0 + r) * EMB + k0 + lcol];
        }
        __syncthreads();
        #pragma unroll
        for (int k = 0; k < 32; ++k) {
            double a[4], b[4];
            #pragma unroll
            for (int i = 0; i < 4; ++i) a[i] = (double)As[ty * 4 + i][k];
            #pragma unroll
            for (int j = 0; j < 4; ++j) b[j] = (double)Bs[tx * 4 + j][k];
            #pragma unroll
            for (int i = 0; i < 4; ++i)
                #pragma unroll
                for (int j = 0; j < 4; ++j) acc[i][j] += a[i] * b[j];
        }
    }
    #pragma unroll
    for (int i = 0; i < 4; ++i) {
        float4 v = make_float4((float)acc[i][0], (float)acc[i][1],
                               (float)acc[i][2], (float)acc[i][3]);
        *reinterpret_cast<float4*>(&C[(size_t)(m0 + ty * 4 + i) * CIN + n0 + tx * 4]) = v;
    }
}

// ================= FUSED: zi (bf16-split MFMA) + prefilter (r13 base) =================
// Block = 64 tokens (4 waves x 16). Phase 1: zi=(z-zq)@W^T, store bf16 h|l packed u32
// to global. Phase 2: top-3 prefilter over 1024 codes. Both phases: 1-barrier
// double-buffered LDS staging; setprio around MFMA clusters (T5).
__global__ __launch_bounds__(256, 2) void fused_k(const float* __restrict__ z,
                                                  const float* __restrict__ zq,
                                                  const u16* __restrict__ wh,
                                                  const u16* __restrict__ wl,
                                                  const u16* __restrict__ cbh,
                                                  const u16* __restrict__ cbl,
                                                  const float* __restrict__ vnorm32,
                                                  u32* __restrict__ zi_hl,
                                                  int* __restrict__ idx,
                                                  int* __restrict__ idx_sum,
                                                  float* __restrict__ mind,
                                                  int* __restrict__ flagged,
                                                  int* __restrict__ cnt,
                                                  int* __restrict__ fullList,
                                                  int* __restrict__ cntF,
                                                  int* __restrict__ cand2,
                                                  double* __restrict__ loss_acc,
                                                  int stage0, int cumprod) {
    __shared__ __align__(16) u16 sbh[2][16][264];
    __shared__ __align__(16) u16 sbl[2][16][264];
    __shared__ double loss_s[16];
    const int tid = threadIdx.x;
    const int w = tid >> 6;
    const int l = tid & 63;
    const int col = l & 15;
    const int g = l >> 4;
    const int mw = blockIdx.x * 64 + w * 16;
    const int sr = tid >> 4, sq = tid & 15;

    // ---------- Phase 1: A fragments from z - zq ----------
    {
        s16x8 ah[16], al[16];
        const float* zr = z  + (size_t)(mw + col) * CIN + g * 8;
        const float* qr = zq + (size_t)(mw + col) * CIN + g * 8;
        #pragma unroll
        for (int kc = 0; kc < 16; ++kc) {
            float4 f0 = *reinterpret_cast<const float4*>(zr + kc * 32);
            float4 f1 = *reinterpret_cast<const float4*>(zr + kc * 32 + 4);
            float f[8] = {f0.x, f0.y, f0.z, f0.w, f1.x, f1.y, f1.z, f1.w};
            if (!stage0) {
                float4 q0 = *reinterpret_cast<const float4*>(qr + kc * 32);
                float4 q1 = *reinterpret_cast<const float4*>(qr + kc * 32 + 4);
                f[0] -= q0.x; f[1] -= q0.y; f[2] -= q0.z; f[3] -= q0.w;
                f[4] -= q1.x; f[5] -= q1.y; f[6] -= q1.z; f[7] -= q1.w;
            }
            #pragma unroll
            for (int j = 0; j < 8; ++j) {
                u16 h, lo; split2(f[j], h, lo);
                ah[kc][j] = (short)h; al[kc][j] = (short)lo;
            }
        }

        // W staging: half-tile S = nt*2 + kh (16 neurons x 256 k), dbuf, 1 barrier/S
        uint4 h0, h1, l0, l1;
#define WLOAD(S) do { int nt_ = (S) >> 1, kh_ = (S) & 1;                               \
    const u16* th = wh + (size_t)(nt_ * 16 + sr) * CIN + kh_ * 256 + sq * 8;           \
    const u16* tl = wl + (size_t)(nt_ * 16 + sr) * CIN + kh_ * 256 + sq * 8;           \
    h0 = *(const uint4*)(th);  h1 = *(const uint4*)(th + 128);                         \
    l0 = *(const uint4*)(tl);  l1 = *(const uint4*)(tl + 128); } while (0)
#define WWRITE(P) do {                                                                 \
    *(uint4*)&sbh[P][sr][sq * 8] = h0;  *(uint4*)&sbh[P][sr][sq * 8 + 128] = h1;       \
    *(uint4*)&sbl[P][sr][sq * 8] = l0;  *(uint4*)&sbl[P][sr][sq * 8 + 128] = l1;       \
    } while (0)
        WLOAD(0); WWRITE(0); WLOAD(1);

        double zn = 0.0;
        for (int nt = 0; nt < 16; ++nt) {
            f32x4 a0 = {0.f, 0.f, 0.f, 0.f};
            f32x4 a1 = {0.f, 0.f, 0.f, 0.f};
            f32x4 a2 = {0.f, 0.f, 0.f, 0.f};
            #pragma unroll
            for (int kh = 0; kh < 2; ++kh) {
                const int S = nt * 2 + kh;
                __syncthreads();                 // buf[S&1] ready; prev reads done
                if (S + 1 < 32) WWRITE((S + 1) & 1);
                if (S + 2 < 32) WLOAD(S + 2);
                __builtin_amdgcn_s_setprio(1);
                #pragma unroll
                for (int kc = 0; kc < 8; ++kc) {
                    s16x8 Bh = *(const s16x8*)&sbh[kh][col][g * 8 + kc * 32];
                    s16x8 Bl = *(const s16x8*)&sbl[kh][col][g * 8 + kc * 32];
                    const int ka = kh * 8 + kc;
                    a0 = __builtin_amdgcn_mfma_f32_16x16x32_bf16(ah[ka], Bh, a0, 0, 0, 0);
                    a1 = __builtin_amdgcn_mfma_f32_16x16x32_bf16(al[ka], Bh, a1, 0, 0, 0);
                    a2 = __builtin_amdgcn_mfma_f32_16x16x32_bf16(ah[ka], Bl, a2, 0, 0, 0);
                }
                __builtin_amdgcn_s_setprio(0);
            }
            #pragma unroll
            for (int r = 0; r < 4; ++r) {
                float v = a0[r] + a1[r] + a2[r];
                u16 h, lo; split2(v, h, lo);
                zi_hl[(size_t)(mw + g * 4 + r) * EMB + nt * 16 + col] =
                    (u32)h | ((u32)lo << 16);
                zn += (double)v * (double)v;
            }
        }
#undef WLOAD
#undef WWRITE
        #pragma unroll
        for (int off = 32; off > 0; off >>= 1) zn += __shfl_down(zn, off, 64);
        if (l == 0) atomicAdd(loss_acc, zn);
    }
    __syncthreads();   // drain zi_hl stores; all phase-1 staging reads done

    // ---------- Phase 2: prefilter ----------
    s16x8 ah[8], al[8];
    {
        const u32* zr = zi_hl + (size_t)(mw + col) * EMB + g * 8;
        #pragma unroll
        for (int kc = 0; kc < 8; ++kc) {
            uint4 u0 = *reinterpret_cast<const uint4*>(zr + kc * 32);
            uint4 u1 = *reinterpret_cast<const uint4*>(zr + kc * 32 + 4);
            u32 u[8] = {u0.x, u0.y, u0.z, u0.w, u1.x, u1.y, u1.z, u1.w};
            #pragma unroll
            for (int j = 0; j < 8; ++j) {
                ah[kc][j] = (short)(u[j] & 0xffffu);
                al[kc][j] = (short)(u[j] >> 16);
            }
        }
    }

    float b1[4] = {1e30f, 1e30f, 1e30f, 1e30f};
    float b2[4] = {1e30f, 1e30f, 1e30f, 1e30f};
    float b3[4] = {1e30f, 1e30f, 1e30f, 1e30f};
    int   i1[4] = {0, 0, 0, 0};
    int   i2[4] = {0, 0, 0, 0};

    uint4 h0, h1, l0, l1;
#define PLOAD(CT) do {                                                                 \
    const u16* th = cbh + (size_t)((CT) * 16 + sr) * EMB + sq * 8;                     \
    const u16* tl = cbl + (size_t)((CT) * 16 + sr) * EMB + sq * 8;                     \
    h0 = *(const uint4*)(th);  h1 = *(const uint4*)(th + 128);                         \
    l0 = *(const uint4*)(tl);  l1 = *(const uint4*)(tl + 128); } while (0)
#define PWRITE(P) do {                                                                 \
    *(uint4*)&sbh[P][sr][sq * 8] = h0;  *(uint4*)&sbh[P][sr][sq * 8 + 128] = h1;       \
    *(uint4*)&sbl[P][sr][sq * 8] = l0;  *(uint4*)&sbl[P][sr][sq * 8 + 128] = l1;       \
    } while (0)
    PLOAD(0); PWRITE(0); PLOAD(1);

    for (int ct = 0; ct < 64; ++ct) {
        __syncthreads();                         // buf[ct&1] ready; prev reads done
        const int p = ct & 1;
        if (ct + 1 < 64) PWRITE((ct + 1) & 1);
        if (ct + 2 < 64) PLOAD(ct + 2);
        const float vn = vnorm32[ct * 16 + col];
        f32x4 a0 = {0.f, 0.f, 0.f, 0.f};
        f32x4 a1 = {0.f, 0.f, 0.f, 0.f};
        f32x4 a2 = {0.f, 0.f, 0.f, 0.f};
        __builtin_amdgcn_s_setprio(1);
        #pragma unroll
        for (int kc = 0; kc < 8; ++kc) {
            s16x8 Bh = *(const s16x8*)&sbh[p][col][g * 8 + kc * 32];
            s16x8 Bl = *(const s16x8*)&sbl[p][col][g * 8 + kc * 32];
            a0 = __builtin_amdgcn_mfma_f32_16x16x32_bf16(ah[kc], Bh, a0, 0, 0, 0);
            a1 = __builtin_amdgcn_mfma_f32_16x16x32_bf16(al[kc], Bh, a1, 0, 0, 0);
            a2 = __builtin_amdgcn_mfma_f32_16x16x32_bf16(ah[kc], Bl, a2, 0, 0, 0);
        }
        __builtin_amdgcn_s_setprio(0);
        #pragma unroll
        for (int r = 0; r < 4; ++r) {
            float sc = vn - 2.f * (a0[r] + a1[r] + a2[r]);
            int c = ct * 16 + col;
            if (sc < b1[r]) { b3[r] = b2[r]; b2[r] = b1[r]; i2[r] = i1[r]; b1[r] = sc; i1[r] = c; }
            else if (sc < b2[r]) { b3[r] = b2[r]; b2[r] = sc; i2[r] = c; }
            else b3[r] = fminf(b3[r], sc);
        }
    }
#undef PLOAD
#undef PWRITE

    // cross-lane top-3 merge over the 16 lanes of each token group
    #pragma unroll
    for (int off = 1; off < 16; off <<= 1) {
        #pragma unroll
        for (int r = 0; r < 4; ++r) {
            float c1 = __shfl_xor(b1[r], off, 64);
            int   j1 = __shfl_xor(i1[r], off, 64);
            float c2 = __shfl_xor(b2[r], off, 64);
            int   j2 = __shfl_xor(i2[r], off, 64);
            float c3 = __shfl_xor(b3[r], off, 64);
            float nb1, nb2, nb3; int ni1, ni2;
            if (c1 < b1[r] || (c1 == b1[r] && j1 < i1[r])) {
                nb1 = c1; ni1 = j1;
                if (b1[r] < c2 || (b1[r] == c2 && i1[r] < j2)) {
                    nb2 = b1[r]; ni2 = i1[r]; nb3 = fminf(b2[r], c2);
                } else {
                    nb2 = c2; ni2 = j2; nb3 = fminf(b1[r], c3);
                }
            } else {
                nb1 = b1[r]; ni1 = i1[r];
                if (c1 < b2[r] || (c1 == b2[r] && j1 < i2[r])) {
                    nb2 = c1; ni2 = j1; nb3 = fminf(b2[r], c2);
                } else {
                    nb2 = b2[r]; ni2 = i2[r]; nb3 = fminf(c1, b3[r]);
                }
            }
            b1[r] = nb1; b2[r] = nb2; b3[r] = nb3; i1[r] = ni1; i2[r] = ni2;
        }
    }
    if (col == 0) {
        double lsum = 0.0;
        #pragma unroll
        for (int r = 0; r < 4; ++r) {
            int m = mw + g * 4 + r;
            idx[m] = i1[r];
            if (stage0) idx_sum[m] = i1[r];
            else        idx_sum[m] += i1[r] * cumprod;
            mind[m] = b1[r];                 // score-only part
            lsum += (double)b1[r];
            if (b2[r] - b1[r] < DELTA) {
                if (b3[r] - b1[r] < DELTA) {
                    int slot = atomicAdd(cntF, 1);
                    fullList[slot] = m;
                } else {
                    int slot = atomicAdd(cnt, 1);
                    flagged[slot] = m;
                    cand2[m] = i2[r];
                }
            }
        }
        loss_s[w * 4 + g] = lsum;
    }
    __syncthreads();
    if (tid == 0) {
        double s = 0.0;
        #pragma unroll
        for (int q = 0; q < 16; ++q) s += loss_s[q];
        atomicAdd(loss_acc, s);
    }
}

// ---------------- exact fp64 pair rescan, batched 8 tokens/block ----------------
__global__ __launch_bounds__(256) void rescan_pair_k(const float* __restrict__ z,
                                                     const float* __restrict__ zqv,
                                                     const float* __restrict__ WinT,
                                                     const float* __restrict__ cb,
                                                     const double* __restrict__ vnorm64,
                                                     const int* __restrict__ flagged,
                                                     const int* __restrict__ cnt,
                                                     const int* __restrict__ cand2,
                                                     int* __restrict__ idx,
                                                     int* __restrict__ idx_sum,
                                                     float* __restrict__ mind,
                                                     double* __restrict__ loss_acc,
                                                     int cumprod, int stage0) {
    __shared__ double r64[8][CIN];           // 32 KB; first 16 KB reused as zi64[8][256]
    __shared__ int mArr[8], cAArr[8], cBArr[8];
    double* zi_l = &r64[0][0];               // alias (used after sync)
    const int tid = threadIdx.x;
    const int w = tid >> 6, l = tid & 63;
    const int n = *cnt;

    for (int jb = blockIdx.x; jb * 8 < n; jb += gridDim.x) {
        const int nt = min(8, n - jb * 8);
        __syncthreads();                     // protect LDS reuse across jb
        if (tid < nt) {
            int m = flagged[jb * 8 + tid];
            mArr[tid] = m;
            cAArr[tid] = idx[m]; cBArr[tid] = cand2[m];
        }
        __syncthreads();
        // stage residuals (coalesced): thread covers k = tid, tid+256
        for (int t = 0; t < nt; ++t) {
            const int m = mArr[t];
            #pragma unroll
            for (int h = 0; h < 2; ++h) {
                int k = tid + h * 256;
                float rv = z[(size_t)m * CIN + k];
                if (!stage0) rv -= zqv[(size_t)m * CIN + k];   // fp32 subtract (matches ref)
                r64[t][k] = (double)rv;
            }
        }
        __syncthreads();
        // zi64: thread e = tid computes 8 dots; WinT rows read coalesced, r64 broadcast
        double acc[8] = {0, 0, 0, 0, 0, 0, 0, 0};
        #pragma unroll 4
        for (int k = 0; k < CIN; ++k) {
            double wv = (double)WinT[(size_t)k * EMB + tid];
            #pragma unroll
            for (int t = 0; t < 8; ++t) acc[t] += r64[t][k] * wv;
        }
        __syncthreads();
        #pragma unroll
        for (int t = 0; t < 8; ++t) zi_l[t * 256 + tid] = acc[t];
        __syncthreads();

        // wave w handles tokens t = w, w+4
        for (int t = w; t < nt; t += 4) {
            const int cA = cAArr[t], cB = cBArr[t], m = mArr[t];
            const double* zt = zi_l + t * 256;
            float4 vA = *(const float4*)(cb + (size_t)cA * EMB + 4 * l);
            float4 vB = *(const float4*)(cb + (size_t)cB * EMB + 4 * l);
            double z0 = zt[4 * l], z1 = zt[4 * l + 1];
            double z2 = zt[4 * l + 2], z3 = zt[4 * l + 3];
            double sA = z0 * (double)vA.x + z1 * (double)vA.y
                      + z2 * (double)vA.z + z3 * (double)vA.w;
            double sB = z0 * (double)vB.x + z1 * (double)vB.y
                      + z2 * (double)vB.z + z3 * (double)vB.w;
            #pragma unroll
            for (int off = 1; off < 64; off <<= 1) {
                sA += __shfl_xor(sA, off, 64);
                sB += __shfl_xor(sB, off, 64);
            }
            if (l == 0) {
                double dA = vnorm64[cA] - 2.0 * sA;
                double dB = vnorm64[cB] - 2.0 * sB;
                int bi; double best;
                if (dB < dA || (dB == dA && cB < cA)) { bi = cB; best = dB; }
                else                                   { bi = cA; best = dA; }
                int oldI = idx[m];
                if (bi != oldI) { idx[m] = bi; idx_sum[m] += (bi - oldI) * cumprod; }
                atomicAdd(loss_acc, best - (double)mind[m]);
                mind[m] = (float)best;
            }
        }
    }
}

// ---------------- exact fp64 full scan, one block per full token, thread-per-code ----------------
__global__ __launch_bounds__(256) void fullscan_k(const float* __restrict__ z,
                                                  const float* __restrict__ zqv,
                                                  const float* __restrict__ WinT,
                                                  const float* __restrict__ cb,
                                                  const double* __restrict__ vnorm64,
                                                  const int* __restrict__ fullList,
                                                  const int* __restrict__ cntF,
                                                  int* __restrict__ idx,
                                                  int* __restrict__ idx_sum,
                                                  float* __restrict__ mind,
                                                  double* __restrict__ loss_acc,
                                                  int cumprod, int stage0) {
    __shared__ double r64[CIN];
    __shared__ double zi64[EMB];
    __shared__ double sred[256];
    __shared__ int ired[256];
    const int tid = threadIdx.x;
    const int n = *cntF;

    for (int j = blockIdx.x; j < n; j += gridDim.x) {
        const int m = fullList[j];
        __syncthreads();                     // protect LDS reuse across j
        #pragma unroll
        for (int h = 0; h < 2; ++h) {
            int k = tid + h * 256;
            float rv = z[(size_t)m * CIN + k];
            if (!stage0) rv -= zqv[(size_t)m * CIN + k];
            r64[k] = (double)rv;
        }
        __syncthreads();
        {
            double acc = 0.0;
            #pragma unroll 8
            for (int k = 0; k < CIN; ++k)
                acc += r64[k] * (double)WinT[(size_t)k * EMB + tid];
            zi64[tid] = acc;
        }
        __syncthreads();
        // thread t scores codes {t, 256+t, 512+t, 768+t} (ascending per thread)
        double best = 1e300; int bi = 0;
        #pragma unroll
        for (int q = 0; q < 4; ++q) {
            const int c = q * 256 + tid;
            const float* row = cb + (size_t)c * EMB;
            double s0 = 0, s1 = 0, s2 = 0, s3 = 0;
            #pragma unroll 4
            for (int e = 0; e < EMB; e += 4) {
                float4 v = *(const float4*)(row + e);
                s0 += zi64[e]     * (double)v.x;
                s1 += zi64[e + 1] * (double)v.y;
                s2 += zi64[e + 2] * (double)v.z;
                s3 += zi64[e + 3] * (double)v.w;
            }
            double sc = vnorm64[c] - 2.0 * ((s0 + s1) + (s2 + s3));
            if (sc < best) { best = sc; bi = c; }
        }
        sred[tid] = best; ired[tid] = bi;
        __syncthreads();
        for (int off = 128; off > 0; off >>= 1) {
            if (tid < off) {
                double ob = sred[tid + off]; int oi = ired[tid + off];
                if (ob < sred[tid] || (ob == sred[tid] && oi < ired[tid])) {
                    sred[tid] = ob; ired[tid] = oi;
                }
            }
            __syncthreads();
        }
        if (tid == 0) {
            int oldI = idx[m], bi2 = ired[0];
            double best2 = sred[0];
            if (bi2 != oldI) { idx[m] = bi2; idx_sum[m] += (bi2 - oldI) * cumprod; }
            atomicAdd(loss_acc, best2 - (double)mind[m]);
            mind[m] = (float)best2;
        }
    }
}

// ---------------- zq (+)= T[idx]  (row gather); last stage also sums (z - zq)^2 ----------------
__global__ __launch_bounds__(256) void gather_k(const float* __restrict__ T,
                                                const int* __restrict__ idx,
                                                const float* __restrict__ z,
                                                float* __restrict__ zq,
                                                int stage0, int last,
                                                double* __restrict__ loss_acc) {
    __shared__ double red[256];
    int m = blockIdx.x * 16 + (threadIdx.x >> 4);
    int q = threadIdx.x & 15;
    const float* src = T + (size_t)idx[m] * CIN;
    float* dst = zq + (size_t)m * CIN;
    double s = 0.0;
    #pragma unroll
    for (int it = 0; it < 8; ++it) {
        int off = it * 64 + q * 4;
        float4 t = *reinterpret_cast<const float4*>(src + off);
        if (!stage0) {
            float4 o = *reinterpret_cast<const float4*>(dst + off);
            t.x += o.x; t.y += o.y; t.z += o.z; t.w += o.w;
        }
        *reinterpret_cast<float4*>(dst + off) = t;
        if (last) {
            float4 zv = *reinterpret_cast<const float4*>(z + (size_t)m * CIN + off);
            double d0 = (double)zv.x - (double)t.x;
            double d1 = (double)zv.y - (double)t.y;
            double d2 = (double)zv.z - (double)t.z;
            double d3 = (double)zv.w - (double)t.w;
            s += d0 * d0 + d1 * d1 + d2 * d2 + d3 * d3;
        }
    }
    if (last) {
        red[threadIdx.x] = s;
        __syncthreads();
        for (int off = 128; off > 0; off >>= 1) {
            if (threadIdx.x < off) red[threadIdx.x] += red[threadIdx.x + off];
            __syncthreads();
        }
        if (threadIdx.x == 0) atomicAdd(loss_acc + 1, red[0]);
    }
}

// ---------------- finalize ----------------
__global__ void final_k(const int* __restrict__ idx_sum,
                        const double* __restrict__ loss_acc,
                        float* __restrict__ out) {
    int i = blockIdx.x * blockDim.x + threadIdx.x;
    if (i < MTOK) out[MTOK * CIN + i] = (float)idx_sum[i];
    if (i == 0) {
        double loss = 2.0 * loss_acc[0] / (3.0 * (double)MTOK * (double)EMB)
                    + loss_acc[1] / ((double)MTOK * (double)CIN);
        out[MTOK * CIN + MTOK] = (float)loss;
    }
}

extern "C" void kernel_launch(void* const* d_in, const int* in_sizes, int n_in,
                              void* d_out, int out_size, void* d_ws, size_t ws_size,
                              hipStream_t stream) {
    const float* z     = (const float*)d_in[0];
    const float* W_in  = (const float*)d_in[1];
    const float* W_out = (const float*)d_in[2];
    const float* cbs   = (const float*)d_in[3];
    float* out = (float*)d_out;
    char* ws = (char*)d_ws;

    // ws layout (16B-aligned)
    double* vnorm64  = (double*)ws;                               // 24576
    double* loss_acc = (double*)(ws + 24576);                     // 16
    int*    cnt      = (int*)(ws + 24592);                        // 32 ([0..2] pair, [3..5] full)
    float*  vnorm32  = (float*)(ws + 24624);                      // 12288 -> 36912
    u16*    cbh      = (u16*)(ws + 36912);                        // 1572864 -> 1609776
    u16*    cbl      = (u16*)(ws + 1609776);                      // 1572864 -> 3182640
    u16*    wh       = (u16*)(ws + 3182640);                      // 786432 -> 3969072
    u16*    wl       = (u16*)(ws + 3969072);                      // 786432 -> 4755504
    float*  WinT     = (float*)(ws + 4755504);                    // 1572864 -> 6328368
    float*  T        = (float*)(ws + 6328368);                    // 6291456 -> 12619824
    u32*    zi_hl    = (u32*)(ws + 12619824);                     // 33554432 -> 46174256
    char*   p        = ws + 46174256;
    int*    idx      = (int*)p;                                   // 131072
    int*    idx_sum  = (int*)(p + 131072);                        // 131072
    int*    flagged  = (int*)(p + 262144);                        // 131072
    float*  mind     = (float*)(p + 393216);                      // 131072
    int*    cand2    = (int*)(p + 524288);                        // 131072
    int*    fullList = (int*)(p + 655360);                        // 131072

    float* zq = out;  // z_q lives in d_out[0 .. MTOK*CIN)

    init_k<<<dim3(1), dim3(1), 0, stream>>>(loss_acc, cnt);
    prep_cb_k<<<dim3(VQ * NCODE), dim3(64), 0, stream>>>(cbs, vnorm64, vnorm32, cbh, cbl);
    prep_w_k<<<dim3(VQ * EMB * CIN / 256), dim3(256), 0, stream>>>(W_in, wh, wl);
    prep_wt_k<<<dim3(VQ * EMB * CIN / 256), dim3(256), 0, stream>>>(W_in, WinT);
    prep_T_k<<<dim3(NCODE / 64, CIN / 64, VQ), dim3(256), 0, stream>>>(cbs, W_out, T);

    const int cumprod[VQ] = {1, 1024, 1024 * 1024};
    for (int i = 0; i < VQ; ++i) {
        const float* cb = cbs + (size_t)i * NCODE * EMB;
        fused_k<<<dim3(MTOK / 64), dim3(256), 0, stream>>>(
            z, zq, wh + (size_t)i * EMB * CIN, wl + (size_t)i * EMB * CIN,
            cbh + (size_t)i * NCODE * EMB, cbl + (size_t)i * NCODE * EMB,
            vnorm32 + i * NCODE, zi_hl, idx, idx_sum, mind, flagged, cnt + i,
            fullList, cnt + 3 + i, cand2, loss_acc, i == 0 ? 1 : 0, cumprod[i]);
        rescan_pair_k<<<dim3(512), dim3(256), 0, stream>>>(
            z, zq, WinT + (size_t)i * EMB * CIN, cb, vnorm64 + i * NCODE,
            flagged, cnt + i, cand2, idx, idx_sum, mind, loss_acc, cumprod[i],
            i == 0 ? 1 : 0);
        fullscan_k<<<dim3(256), dim3(256), 0, stream>>>(
            z, zq, WinT + (size_t)i * EMB * CIN, cb, vnorm64 + i * NCODE,
            fullList, cnt + 3 + i, idx, idx_sum, mind, loss_acc, cumprod[i],
            i == 0 ? 1 : 0);
        gather_k<<<dim3(MTOK / 16), dim3(256), 0, stream>>>(
            T + (size_t)i * NCODE * CIN, idx, z, zq, i == 0 ? 1 : 0,
            i == VQ - 1 ? 1 : 0, loss_acc);
    }
    final_k<<<dim3(MTOK / 256), dim3(256), 0, stream>>>(idx_sum, loss_acc, out);
}